// Round 2
// baseline (1172.915 us; speedup 1.0000x reference)
//
#include <hip/hip_runtime.h>

#define BB 8
#define C 96
#define HH 192
#define WW 192
#define NPIX (HH*WW)          // 36864
#define C3 (3*C)              // 288
#define NHEADS 3
#define CHD 32
#define FFND 192
#define EPSV 1e-6f

typedef unsigned short u16;
typedef unsigned int u32;

__device__ __forceinline__ float b2f(u16 h) {
  u32 u = ((u32)h) << 16;
  return __builtin_bit_cast(float, u);
}
__device__ __forceinline__ u16 f2b(float f) {
  u32 u = __builtin_bit_cast(u32, f);
  u32 r = (u + 0x7FFFu + ((u >> 16) & 1u)) >> 16;
  return (u16)r;
}

// ---------------------------------------------------------------------------
// Kernel 1: fused LN1 + qkv 1x1 conv (96 -> 288), output bf16
// grid: cb * (NPIX/128) blocks; local batch bl, global batch b0+bl
// ---------------------------------------------------------------------------
__global__ __launch_bounds__(256) void k_ln1_qkv(
    const float* __restrict__ x, const float* __restrict__ ln1w,
    const float* __restrict__ ln1b, const float* __restrict__ qw,
    const float* __restrict__ qb, u16* __restrict__ qkv_pre, int b0)
{
  __shared__ float xs[C][128];
  __shared__ float mu_s[128], rs_s[128];
  __shared__ float lw[C], lb[C];
  const int tid = threadIdx.x;
  const int nt = NPIX / 128;            // 288 tiles per batch
  const int bl = blockIdx.x / nt;
  const int tile = blockIdx.x % nt;
  const long n0 = (long)tile * 128;
  const float* xb = x + (long)(b0 + bl) * C * NPIX + n0;
  for (int i = tid; i < C * 128; i += 256) {
    int c = i >> 7, j = i & 127;
    xs[c][j] = xb[(long)c * NPIX + j];
  }
  if (tid < C) { lw[tid] = ln1w[tid]; lb[tid] = ln1b[tid]; }
  __syncthreads();
  if (tid < 128) {
    float s = 0.f, ss = 0.f;
    #pragma unroll
    for (int c = 0; c < C; c++) { float v = xs[c][tid]; s += v; ss += v * v; }
    float m = s * (1.f / C);
    float var = ss * (1.f / C) - m * m;
    mu_s[tid] = m;
    rs_s[tid] = rsqrtf(var + EPSV);
  }
  __syncthreads();
  for (int i = tid; i < C * 128; i += 256) {
    int c = i >> 7, j = i & 127;
    xs[c][j] = (xs[c][j] - mu_s[j]) * rs_s[j] * lw[c] + lb[c];
  }
  __syncthreads();
  const int pq = tid & 31;   // position quad: columns 4*pq..4*pq+3
  const int oblk = tid >> 5; // 0..7
  for (int s = 0; s < 6; s++) {
    float4 acc[6];
    #pragma unroll
    for (int t = 0; t < 6; t++) {
      float bv = qb[oblk + 8 * (6 * s + t)];
      acc[t].x = bv; acc[t].y = bv; acc[t].z = bv; acc[t].w = bv;
    }
    #pragma unroll 4
    for (int c = 0; c < C; c++) {
      float4 xv = *reinterpret_cast<const float4*>(&xs[c][pq * 4]);
      #pragma unroll
      for (int t = 0; t < 6; t++) {
        float w = qw[(oblk + 8 * (6 * s + t)) * C + c];
        acc[t].x += w * xv.x; acc[t].y += w * xv.y;
        acc[t].z += w * xv.z; acc[t].w += w * xv.w;
      }
    }
    #pragma unroll
    for (int t = 0; t < 6; t++) {
      int o = oblk + 8 * (6 * s + t);
      ushort4 pk;
      pk.x = f2b(acc[t].x); pk.y = f2b(acc[t].y);
      pk.z = f2b(acc[t].z); pk.w = f2b(acc[t].w);
      *reinterpret_cast<ushort4*>(qkv_pre + ((long)bl * C3 + o) * NPIX + n0 + pq * 4) = pk;
    }
  }
}

// ---------------------------------------------------------------------------
// Kernel 2: depthwise 3x3 SAME, bf16 -> bf16. One thread = 4 consecutive w.
// grid covers cb local batches.
// ---------------------------------------------------------------------------
__global__ __launch_bounds__(256) void k_dwconv(
    const u16* __restrict__ src, const float* __restrict__ dww,
    const float* __restrict__ dwb, u16* __restrict__ dst)
{
  long qid = (long)blockIdx.x * 256 + threadIdx.x;
  int wq = (int)(qid % 48);
  long t = qid / 48;
  int h = (int)(t % HH); t /= HH;
  int ch = (int)(t % C3);
  int bl = (int)(t / C3);
  const u16* p = src + ((long)bl * C3 + ch) * NPIX;
  float wgt[9];
  #pragma unroll
  for (int i = 0; i < 9; i++) wgt[i] = dww[ch * 9 + i];
  float acc0 = 0.f, acc1 = 0.f, acc2 = 0.f, acc3 = 0.f;
  int w0 = wq * 4;
  #pragma unroll
  for (int dh = -1; dh <= 1; dh++) {
    int hh = h + dh;
    if (hh < 0 || hh >= HH) continue;
    const u16* row = p + (long)hh * WW;
    ushort4 v4 = *reinterpret_cast<const ushort4*>(row + w0);
    float r0 = (w0 > 0) ? b2f(row[w0 - 1]) : 0.f;
    float r1 = b2f(v4.x), r2 = b2f(v4.y), r3 = b2f(v4.z), r4v = b2f(v4.w);
    float r5 = (w0 + 4 < WW) ? b2f(row[w0 + 4]) : 0.f;
    float wA = wgt[(dh + 1) * 3 + 0];
    float wB = wgt[(dh + 1) * 3 + 1];
    float wC = wgt[(dh + 1) * 3 + 2];
    acc0 += r0 * wA + r1 * wB + r2 * wC;
    acc1 += r1 * wA + r2 * wB + r3 * wC;
    acc2 += r2 * wA + r3 * wB + r4v * wC;
    acc3 += r3 * wA + r4v * wB + r5 * wC;
  }
  float bb = dwb[ch];
  ushort4 o4;
  o4.x = f2b(acc0 + bb); o4.y = f2b(acc1 + bb);
  o4.z = f2b(acc2 + bb); o4.w = f2b(acc3 + bb);
  *reinterpret_cast<ushort4*>(dst + ((long)bl * C3 + ch) * NPIX + (long)h * WW + w0) = o4;
}

// ---------------------------------------------------------------------------
// Kernel 3: Gram matrix G[c][d] = sum_n q_c[n] k_d[n] and row sumsq, atomics.
// One block = one (bl, head, chunk of 192 positions). G indexed by GLOBAL bh.
// ---------------------------------------------------------------------------
#define GCHUNK 192
__global__ __launch_bounds__(256) void k_gram(
    const u16* __restrict__ qkv, float* __restrict__ G,
    float* __restrict__ nq, float* __restrict__ nk, int b0)
{
  __shared__ float qs[GCHUNK * 33];
  __shared__ float ks[GCHUNK * 33];
  const int tid = threadIdx.x;
  const int nchunks = NPIX / GCHUNK;  // 192
  const int bhl = blockIdx.x / nchunks;     // local (bl*3+hd)
  const int chunk = blockIdx.x % nchunks;
  const int bl = bhl / NHEADS, hd = bhl % NHEADS;
  const int bh = (b0 + bl) * NHEADS + hd;   // global
  const long n0 = (long)chunk * GCHUNK;
  const u16* qbase = qkv + ((long)bl * C3 + hd * CHD) * NPIX + n0;
  const u16* kbase = qkv + ((long)bl * C3 + C + hd * CHD) * NPIX + n0;
  for (int i = tid; i < CHD * GCHUNK; i += 256) {
    int c = i / GCHUNK, j = i % GCHUNK;
    qs[j * 33 + c] = b2f(qbase[(long)c * NPIX + j]);
    ks[j * 33 + c] = b2f(kbase[(long)c * NPIX + j]);
  }
  __syncthreads();
  if (tid < 64) {
    int r = tid & 31;
    const float* src = (tid < 32) ? qs : ks;
    float s = 0.f;
    for (int j = 0; j < GCHUNK; j++) { float v = src[j * 33 + r]; s += v * v; }
    atomicAdd((tid < 32) ? &nq[bh * CHD + r] : &nk[bh * CHD + r], s);
  }
  const int d = tid & 31, cb = tid >> 5;  // cb 0..7
  float a0 = 0.f, a1 = 0.f, a2 = 0.f, a3 = 0.f;
  for (int j = 0; j < GCHUNK; j++) {
    float kv = ks[j * 33 + d];
    a0 += qs[j * 33 + cb + 0]  * kv;
    a1 += qs[j * 33 + cb + 8]  * kv;
    a2 += qs[j * 33 + cb + 16] * kv;
    a3 += qs[j * 33 + cb + 24] * kv;
  }
  atomicAdd(&G[bh * 1024 + (cb + 0)  * 32 + d], a0);
  atomicAdd(&G[bh * 1024 + (cb + 8)  * 32 + d], a1);
  atomicAdd(&G[bh * 1024 + (cb + 16) * 32 + d], a2);
  atomicAdd(&G[bh * 1024 + (cb + 24) * 32 + d], a3);
}

// ---------------------------------------------------------------------------
// Kernel 4: normalize + relu + softmax -> A.  cb*3 blocks x 32 threads.
// ---------------------------------------------------------------------------
__global__ void k_softmax(const float* __restrict__ G, const float* __restrict__ nq,
                          const float* __restrict__ nk, const float* __restrict__ temp,
                          float* __restrict__ A, int b0)
{
  int bh = b0 * NHEADS + blockIdx.x;
  int c = threadIdx.x;          // 32 rows
  int hd = bh % NHEADS;
  float tmp = temp[hd];
  float nqc = fmaxf(sqrtf(nq[bh * CHD + c]), 1e-12f);
  float a[32];
  float m = 0.f;
  #pragma unroll
  for (int d = 0; d < 32; d++) {
    float nkd = fmaxf(sqrtf(nk[bh * CHD + d]), 1e-12f);
    float v = G[bh * 1024 + c * 32 + d] / (nqc * nkd) * tmp;
    v = fmaxf(v, 0.f);
    a[d] = v;
    m = fmaxf(m, v);
  }
  float s = 0.f;
  #pragma unroll
  for (int d = 0; d < 32; d++) { a[d] = expf(a[d] - m); s += a[d]; }
  float inv = 1.f / s;
  #pragma unroll
  for (int d = 0; d < 32; d++) A[bh * 1024 + c * 32 + d] = a[d] * inv;
}

// ---------------------------------------------------------------------------
// Kernel 5: out = A @ v, then proj 1x1 (96->96), y = x + out*betac -> d_out.
// One block = 64 positions of one (local) batch.
// ---------------------------------------------------------------------------
__global__ __launch_bounds__(256) void k_av_proj(
    const u16* __restrict__ qkv, const float* __restrict__ A,
    const float* __restrict__ pw, const float* __restrict__ pb,
    const float* __restrict__ x, const float* __restrict__ betac,
    float* __restrict__ y, int b0)
{
  __shared__ float vs[C][64];
  __shared__ float os[C][64];
  __shared__ float As[NHEADS * CHD * CHD];
  const int tid = threadIdx.x;
  const int nt = NPIX / 64;   // 576
  const int bl = blockIdx.x / nt;
  const int tile = blockIdx.x % nt;
  const int b = b0 + bl;
  const long n0 = (long)tile * 64;
  const u16* vb = qkv + ((long)bl * C3 + 2 * C) * NPIX + n0;
  for (int i = tid; i < C * 64; i += 256) {
    int c = i >> 6, j = i & 63;
    vs[c][j] = b2f(vb[(long)c * NPIX + j]);
  }
  for (int i = tid; i < NHEADS * CHD * CHD; i += 256)
    As[i] = A[(long)b * (NHEADS * CHD * CHD) + i];
  __syncthreads();
  const int pq = tid & 15;
  const int og = tid >> 4;   // 0..15
  {
    float4 acc[6];
    #pragma unroll
    for (int t = 0; t < 6; t++) { acc[t].x = acc[t].y = acc[t].z = acc[t].w = 0.f; }
    #pragma unroll 2
    for (int d = 0; d < CHD; d++) {
      #pragma unroll
      for (int t = 0; t < 6; t++) {
        int c = og + 16 * t;
        int row = ((c >> 5) << 5) + d;
        float a = As[(c >> 5) * 1024 + (c & 31) * 32 + d];
        float4 vv = *reinterpret_cast<const float4*>(&vs[row][pq * 4]);
        acc[t].x += a * vv.x; acc[t].y += a * vv.y;
        acc[t].z += a * vv.z; acc[t].w += a * vv.w;
      }
    }
    #pragma unroll
    for (int t = 0; t < 6; t++) {
      int c = og + 16 * t;
      *reinterpret_cast<float4*>(&os[c][pq * 4]) = acc[t];
    }
  }
  __syncthreads();
  {
    float4 acc[6];
    #pragma unroll
    for (int t = 0; t < 6; t++) {
      float bv = pb[og + 16 * t];
      acc[t].x = bv; acc[t].y = bv; acc[t].z = bv; acc[t].w = bv;
    }
    #pragma unroll 4
    for (int c = 0; c < C; c++) {
      float4 ov = *reinterpret_cast<const float4*>(&os[c][pq * 4]);
      #pragma unroll
      for (int t = 0; t < 6; t++) {
        float w = pw[(og + 16 * t) * C + c];
        acc[t].x += w * ov.x; acc[t].y += w * ov.y;
        acc[t].z += w * ov.z; acc[t].w += w * ov.w;
      }
    }
    #pragma unroll
    for (int t = 0; t < 6; t++) {
      int o = og + 16 * t;
      float bt = betac[o];
      const float4 xv = *reinterpret_cast<const float4*>(
          x + ((long)b * C + o) * NPIX + n0 + pq * 4);
      float4 yv;
      yv.x = xv.x + acc[t].x * bt;
      yv.y = xv.y + acc[t].y * bt;
      yv.z = xv.z + acc[t].z * bt;
      yv.w = xv.w + acc[t].w * bt;
      *reinterpret_cast<float4*>(y + ((long)b * C + o) * NPIX + n0 + pq * 4) = yv;
    }
  }
}

// ---------------------------------------------------------------------------
// Kernel 6: fold LN2 into conv1 weights. W' = c1w * ln2w; S1 = sum W';
// S2 = sum c1w * ln2b. One small block.
// ---------------------------------------------------------------------------
__global__ void k_fold(const float* __restrict__ c1w, const float* __restrict__ ln2w,
                       const float* __restrict__ ln2b, float* __restrict__ Wp,
                       float* __restrict__ S1, float* __restrict__ S2)
{
  int o = threadIdx.x;
  if (o >= FFND) return;
  float s1 = 0.f, s2 = 0.f;
  for (int c = 0; c < C; c++) {
    float w = c1w[o * C + c];
    float wp = w * ln2w[c];
    Wp[o * C + c] = wp;
    s1 += wp;
    s2 += w * ln2b[c];
  }
  S1[o] = s1;
  S2[o] = s2;
}

// ---------------------------------------------------------------------------
// Kernel 7: fused LN2 (folded) + conv1 (96->192) + gate + conv2 (96->96)
//           + residual.  Reads y from d_out tile, writes out to same tile.
// ---------------------------------------------------------------------------
__global__ __launch_bounds__(256) void k_ffn(
    float* __restrict__ y, const float* __restrict__ Wp,
    const float* __restrict__ S1, const float* __restrict__ S2,
    const float* __restrict__ c1b, const float* __restrict__ c2w,
    const float* __restrict__ c2b, const float* __restrict__ gamma)
{
  __shared__ float ys[C][64];
  __shared__ float fs[C][64];
  __shared__ float mu_s[64], rs_s[64];
  const int tid = threadIdx.x;
  const int nt = NPIX / 64;
  const int b = blockIdx.x / nt;
  const int tile = blockIdx.x % nt;
  const long n0 = (long)tile * 64;
  float* yb = y + (long)b * C * NPIX + n0;
  for (int i = tid; i < C * 64; i += 256) {
    int c = i >> 6, j = i & 63;
    ys[c][j] = yb[(long)c * NPIX + j];
  }
  __syncthreads();
  if (tid < 64) {
    float s = 0.f, ss = 0.f;
    #pragma unroll
    for (int c = 0; c < C; c++) { float v = ys[c][tid]; s += v; ss += v * v; }
    float m = s * (1.f / C);
    float var = ss * (1.f / C) - m * m;
    mu_s[tid] = m;
    rs_s[tid] = rsqrtf(var + EPSV);
  }
  __syncthreads();
  const int pq = tid & 15;
  const int og = tid >> 4;   // 0..15
  const float4 mu4 = *reinterpret_cast<const float4*>(&mu_s[pq * 4]);
  const float4 r4  = *reinterpret_cast<const float4*>(&rs_s[pq * 4]);
  for (int s = 0; s < 2; s++) {
    float4 alo[3], ahi[3];
    #pragma unroll
    for (int t = 0; t < 3; t++) {
      alo[t].x = alo[t].y = alo[t].z = alo[t].w = 0.f;
      ahi[t].x = ahi[t].y = ahi[t].z = ahi[t].w = 0.f;
    }
    #pragma unroll 4
    for (int c = 0; c < C; c++) {
      float4 yv = *reinterpret_cast<const float4*>(&ys[c][pq * 4]);
      #pragma unroll
      for (int t = 0; t < 3; t++) {
        int o = og + 16 * (3 * s + t);
        float wl = Wp[o * C + c];
        float wh = Wp[(o + C) * C + c];
        alo[t].x += wl * yv.x; alo[t].y += wl * yv.y;
        alo[t].z += wl * yv.z; alo[t].w += wl * yv.w;
        ahi[t].x += wh * yv.x; ahi[t].y += wh * yv.y;
        ahi[t].z += wh * yv.z; ahi[t].w += wh * yv.w;
      }
    }
    #pragma unroll
    for (int t = 0; t < 3; t++) {
      int o = og + 16 * (3 * s + t);
      float blo = c1b[o] + S2[o], s1l = S1[o];
      float bhi = c1b[o + C] + S2[o + C], s1h = S1[o + C];
      float4 f;
      f.x = (blo + r4.x * (alo[t].x - mu4.x * s1l)) * (bhi + r4.x * (ahi[t].x - mu4.x * s1h));
      f.y = (blo + r4.y * (alo[t].y - mu4.y * s1l)) * (bhi + r4.y * (ahi[t].y - mu4.y * s1h));
      f.z = (blo + r4.z * (alo[t].z - mu4.z * s1l)) * (bhi + r4.z * (ahi[t].z - mu4.z * s1h));
      f.w = (blo + r4.w * (alo[t].w - mu4.w * s1l)) * (bhi + r4.w * (ahi[t].w - mu4.w * s1h));
      *reinterpret_cast<float4*>(&fs[o][pq * 4]) = f;
    }
  }
  __syncthreads();
  {
    float4 acc[6];
    #pragma unroll
    for (int t = 0; t < 6; t++) { acc[t].x = acc[t].y = acc[t].z = acc[t].w = 0.f; }
    #pragma unroll 4
    for (int j = 0; j < C; j++) {
      float4 fv = *reinterpret_cast<const float4*>(&fs[j][pq * 4]);
      #pragma unroll
      for (int t = 0; t < 6; t++) {
        float w = c2w[(og + 16 * t) * C + j];
        acc[t].x += w * fv.x; acc[t].y += w * fv.y;
        acc[t].z += w * fv.z; acc[t].w += w * fv.w;
      }
    }
    #pragma unroll
    for (int t = 0; t < 6; t++) {
      int o = og + 16 * t;
      float g = gamma[o], cb2 = c2b[o];
      float4 yv = *reinterpret_cast<const float4*>(&ys[o][pq * 4]);
      float4 ov;
      ov.x = yv.x + (acc[t].x + cb2) * g;
      ov.y = yv.y + (acc[t].y + cb2) * g;
      ov.z = yv.z + (acc[t].z + cb2) * g;
      ov.w = yv.w + (acc[t].w + cb2) * g;
      *reinterpret_cast<float4*>(yb + (long)o * NPIX + pq * 4) = ov;
    }
  }
}

// ---------------------------------------------------------------------------
extern "C" void kernel_launch(void* const* d_in, const int* in_sizes, int n_in,
                              void* d_out, int out_size, void* d_ws, size_t ws_size,
                              hipStream_t stream)
{
  const float* x     = (const float*)d_in[0];
  const float* ln1w  = (const float*)d_in[1];
  const float* ln1b  = (const float*)d_in[2];
  const float* ln2w  = (const float*)d_in[3];
  const float* ln2b  = (const float*)d_in[4];
  const float* qkvw  = (const float*)d_in[5];
  const float* qkvb  = (const float*)d_in[6];
  const float* dww   = (const float*)d_in[7];
  const float* dwb   = (const float*)d_in[8];
  const float* temp  = (const float*)d_in[9];
  const float* pw    = (const float*)d_in[10];
  const float* pb    = (const float*)d_in[11];
  const float* c1w   = (const float*)d_in[12];
  const float* c1b   = (const float*)d_in[13];
  const float* c2w   = (const float*)d_in[14];
  const float* c2b   = (const float*)d_in[15];
  const float* betac = (const float*)d_in[16];
  const float* gamma = (const float*)d_in[17];
  float* out = (float*)d_out;   // doubles as y storage

  char* ws = (char*)d_ws;
  size_t off = 0;
  // small persistent buffers first
  float* G  = (float*)(ws + off); off += (size_t)BB * NHEADS * 1024 * sizeof(float);
  float* nq = (float*)(ws + off); off += (size_t)BB * NHEADS * CHD * sizeof(float);
  float* nk = (float*)(ws + off); off += (size_t)BB * NHEADS * CHD * sizeof(float);
  float* A  = (float*)(ws + off); off += (size_t)BB * NHEADS * 1024 * sizeof(float);
  float* Wp = (float*)(ws + off); off += (size_t)FFND * C * sizeof(float);
  float* S1 = (float*)(ws + off); off += FFND * sizeof(float);
  float* S2 = (float*)(ws + off); off += FFND * sizeof(float);
  const size_t small_bytes = off;

  // choose batch-chunk size cb in {8,4,2,1}: qkv_pre + qkv bf16 per batch
  const size_t per_batch = 2 * (size_t)C3 * NPIX * sizeof(u16);  // ~40.5 MB
  int cb = 8;
  while (cb > 1 && small_bytes + (size_t)cb * per_batch > ws_size) cb >>= 1;
  if (small_bytes + (size_t)cb * per_batch > ws_size) return;  // < 41 MB ws

  u16* qkv_pre = (u16*)(ws + off);
  u16* qkv     = qkv_pre + (size_t)cb * C3 * NPIX;

  // zero the atomic accumulators (G, nq, nk contiguous)
  hipMemsetAsync(G, 0, (size_t)(BB * NHEADS * 1024 + 2 * BB * NHEADS * CHD) * sizeof(float),
                 stream);

  k_fold<<<1, 192, 0, stream>>>(c1w, ln2w, ln2b, Wp, S1, S2);

  for (int b0 = 0; b0 < BB; b0 += cb) {
    k_ln1_qkv<<<cb * (NPIX / 128), 256, 0, stream>>>(x, ln1w, ln1b, qkvw, qkvb,
                                                     qkv_pre, b0);
    long quads = (long)cb * C3 * HH * (WW / 4);
    k_dwconv<<<(int)(quads / 256), 256, 0, stream>>>(qkv_pre, dww, dwb, qkv);
    k_gram<<<cb * NHEADS * (NPIX / GCHUNK), 256, 0, stream>>>(qkv, G, nq, nk, b0);
    k_softmax<<<cb * NHEADS, 32, 0, stream>>>(G, nq, nk, temp, A, b0);
    k_av_proj<<<cb * (NPIX / 64), 256, 0, stream>>>(qkv, A, pw, pb, x, betac, out, b0);
  }

  k_ffn<<<BB * (NPIX / 64), 256, 0, stream>>>(out, Wp, S1, S2, c1b, c2w, c2b, gamma);
}

// Round 4
// 718.111 us; speedup vs baseline: 1.6333x; 1.6333x over previous
//
#include <hip/hip_runtime.h>

#define BB 8
#define C 96
#define HH 192
#define WW 192
#define NPIX (HH*WW)          // 36864
#define C3 (3*C)              // 288
#define NHEADS 3
#define FFND 192
#define EPSV 1e-6f
#define PT 64                 // position tile for GEMM kernels
#define GNB 768               // gram n-block

typedef unsigned short u16;
typedef unsigned int u32;
typedef __attribute__((ext_vector_type(8))) short bf16x8;
typedef __attribute__((ext_vector_type(4))) float f32x4;

__device__ __forceinline__ float b2f(u16 h) {
  u32 u = ((u32)h) << 16;
  return __builtin_bit_cast(float, u);
}
__device__ __forceinline__ u16 f2b(float f) {
  u32 u = __builtin_bit_cast(u32, f);
  u32 r = (u + 0x7FFFu + ((u >> 16) & 1u)) >> 16;
  return (u16)r;
}
__device__ __forceinline__ u32 pk2(float a, float b) {
  return (u32)f2b(a) | ((u32)f2b(b) << 16);
}

// Weight fragment layout: for W[O][96] row-major fp32, fragment f = mt*3+kt,
// lane slot l, elem j holds W[mt*16 + (l&15)][kt*32 + 8*(l>>4) + j] as bf16.
// Offsets in Wf (elements): qkv 0, proj 27648, c1 36864, c2 55296.

// ---------------------------------------------------------------------------
// Prep: convert all 1x1-conv weights to fragment-ready bf16
// ---------------------------------------------------------------------------
__global__ __launch_bounds__(256) void k_prep(
    const float* __restrict__ qkvw, const float* __restrict__ pw,
    const float* __restrict__ c1w, const float* __restrict__ c2w,
    u16* __restrict__ Wf)
{
  int t = blockIdx.x * 256 + threadIdx.x;   // lane-frag id, 8064 total
  const float* src; u16* dst; int tl;
  if (t < 3456)      { src = qkvw; dst = Wf;         tl = t; }
  else if (t < 4608) { src = pw;   dst = Wf + 27648; tl = t - 3456; }
  else if (t < 6912) { src = c1w;  dst = Wf + 36864; tl = t - 4608; }
  else if (t < 8064) { src = c2w;  dst = Wf + 55296; tl = t - 6912; }
  else return;
  int fid = tl >> 6, lane = tl & 63;
  int mt = fid / 3, kt = fid % 3;
  int row = mt * 16 + (lane & 15), k0 = kt * 32 + (lane >> 4) * 8;
  const float* s = src + row * 96 + k0;
  uint4 v;
  v.x = pk2(s[0], s[1]); v.y = pk2(s[2], s[3]);
  v.z = pk2(s[4], s[5]); v.w = pk2(s[6], s[7]);
  *reinterpret_cast<uint4*>(dst + (size_t)tl * 8) = v;
}

// ---------------------------------------------------------------------------
// Kernel 1: LN1 + qkv conv (96->288) via MFMA, out bf16 qkv_pre
// ---------------------------------------------------------------------------
__global__ __launch_bounds__(256) void k_ln1_qkv(
    const float* __restrict__ x, const float* __restrict__ ln1w,
    const float* __restrict__ ln1b, const u16* __restrict__ Wf,
    const float* __restrict__ qb, u16* __restrict__ qkv_pre, int b0)
{
  __shared__ float xs[C][PT + 1];
  __shared__ __align__(16) u16 xt[PT][104];
  __shared__ float mu_s[PT], rs_s[PT];
  __shared__ float lw[C], lb[C];
  const int tid = threadIdx.x;
  const int nt = NPIX / PT;            // 576
  const int bl = blockIdx.x / nt;
  const int tile = blockIdx.x % nt;
  const int n0 = tile * PT;
  const float* xb = x + (size_t)(b0 + bl) * C * NPIX + n0;
  for (int i = tid; i < C * PT; i += 256) {
    int c = i >> 6, p = i & 63;
    xs[c][p] = xb[(size_t)c * NPIX + p];
  }
  if (tid < C) { lw[tid] = ln1w[tid]; lb[tid] = ln1b[tid]; }
  __syncthreads();
  float* red = (float*)xt;   // scratch [8][64] inside xt (written later)
  {
    int g = tid >> 6, p = tid & 63;
    float s = 0.f, ss = 0.f;
    for (int c = g * 24; c < g * 24 + 24; c++) { float v = xs[c][p]; s += v; ss += v * v; }
    red[g * 64 + p] = s; red[(4 + g) * 64 + p] = ss;
  }
  __syncthreads();
  if (tid < PT) {
    float s  = red[tid] + red[64 + tid] + red[128 + tid] + red[192 + tid];
    float ss = red[256 + tid] + red[320 + tid] + red[384 + tid] + red[448 + tid];
    float m = s * (1.f / C);
    float var = ss * (1.f / C) - m * m;
    mu_s[tid] = m; rs_s[tid] = rsqrtf(var + EPSV);
  }
  __syncthreads();
  for (int i = tid; i < C * PT; i += 256) {
    int c = i >> 6, p = i & 63;
    xt[p][c] = f2b((xs[c][p] - mu_s[p]) * rs_s[p] * lw[c] + lb[c]);
  }
  __syncthreads();
  const int lane = tid & 63, wv = tid >> 6;
  const int lr = lane & 15, lg = lane >> 4;
  const int pcol = wv * 16 + lr;
  bf16x8 bf[3];
  #pragma unroll
  for (int kt = 0; kt < 3; kt++)
    bf[kt] = *reinterpret_cast<const bf16x8*>(&xt[pcol][kt * 32 + lg * 8]);
  const bf16x8* wfp = reinterpret_cast<const bf16x8*>(Wf);
  u16* outb = qkv_pre + (size_t)bl * C3 * NPIX + n0 + pcol;
  for (int mt = 0; mt < 18; mt++) {
    f32x4 acc = {0.f, 0.f, 0.f, 0.f};
    #pragma unroll
    for (int kt = 0; kt < 3; kt++)
      acc = __builtin_amdgcn_mfma_f32_16x16x32_bf16(wfp[(mt * 3 + kt) * 64 + lane], bf[kt], acc, 0, 0, 0);
    #pragma unroll
    for (int r = 0; r < 4; r++) {
      int o = mt * 16 + lg * 4 + r;
      outb[(size_t)o * NPIX] = f2b(acc[r] + qb[o]);
    }
  }
}

// ---------------------------------------------------------------------------
// Kernel 2: depthwise 3x3 SAME, bf16 -> bf16. One thread = 4 consecutive w.
// ---------------------------------------------------------------------------
__global__ __launch_bounds__(256) void k_dwconv(
    const u16* __restrict__ src, const float* __restrict__ dww,
    const float* __restrict__ dwb, u16* __restrict__ dst)
{
  long qid = (long)blockIdx.x * 256 + threadIdx.x;
  int wq = (int)(qid % 48);
  long t = qid / 48;
  int h = (int)(t % HH); t /= HH;
  int ch = (int)(t % C3);
  int bl = (int)(t / C3);
  const u16* p = src + ((size_t)bl * C3 + ch) * NPIX;
  float wgt[9];
  #pragma unroll
  for (int i = 0; i < 9; i++) wgt[i] = dww[ch * 9 + i];
  float acc0 = 0.f, acc1 = 0.f, acc2 = 0.f, acc3 = 0.f;
  int w0 = wq * 4;
  #pragma unroll
  for (int dh = -1; dh <= 1; dh++) {
    int hh = h + dh;
    if (hh < 0 || hh >= HH) continue;
    const u16* row = p + (size_t)hh * WW;
    ushort4 v4 = *reinterpret_cast<const ushort4*>(row + w0);
    float r0 = (w0 > 0) ? b2f(row[w0 - 1]) : 0.f;
    float r1 = b2f(v4.x), r2 = b2f(v4.y), r3 = b2f(v4.z), r4v = b2f(v4.w);
    float r5 = (w0 + 4 < WW) ? b2f(row[w0 + 4]) : 0.f;
    float wA = wgt[(dh + 1) * 3 + 0];
    float wB = wgt[(dh + 1) * 3 + 1];
    float wC = wgt[(dh + 1) * 3 + 2];
    acc0 += r0 * wA + r1 * wB + r2 * wC;
    acc1 += r1 * wA + r2 * wB + r3 * wC;
    acc2 += r2 * wA + r3 * wB + r4v * wC;
    acc3 += r3 * wA + r4v * wB + r5 * wC;
  }
  float bb = dwb[ch];
  ushort4 o4;
  o4.x = f2b(acc0 + bb); o4.y = f2b(acc1 + bb);
  o4.z = f2b(acc2 + bb); o4.w = f2b(acc3 + bb);
  *reinterpret_cast<ushort4*>(dst + ((size_t)bl * C3 + ch) * NPIX + (size_t)h * WW + w0) = o4;
}

// ---------------------------------------------------------------------------
// Kernel 3: Gram G[c][d] = sum_n q_c[n] k_d[n] via MFMA (contract over n),
// plus row sumsq for q,k. Direct global frag loads, LDS wave-reduce, atomics.
// ---------------------------------------------------------------------------
__global__ __launch_bounds__(256) void k_gram(
    const u16* __restrict__ qkv, float* __restrict__ G,
    float* __restrict__ nq, float* __restrict__ nk, int b0)
{
  __shared__ float gred[4][1024];
  const int tid = threadIdx.x, lane = tid & 63, wv = tid >> 6;
  const int nch = NPIX / GNB;    // 48
  const int bhl = blockIdx.x / nch;
  const int chunk = blockIdx.x % nch;
  const int bl = bhl / NHEADS, hd = bhl % NHEADS;
  const int bh = (b0 + bl) * NHEADS + hd;
  const int lr = lane & 15, lg = lane >> 4;
  const u16* qb_ = qkv + ((size_t)bl * C3 + hd * 32) * NPIX;
  const u16* kb_ = qkv + ((size_t)bl * C3 + C + hd * 32) * NPIX;
  const int nbase = chunk * GNB + wv * (GNB / 4);
  f32x4 a00 = {0,0,0,0}, a01 = {0,0,0,0}, a10 = {0,0,0,0}, a11 = {0,0,0,0};
  float sq0 = 0.f, sq1 = 0.f, sk0 = 0.f, sk1 = 0.f;
  #pragma unroll 2
  for (int it = 0; it < GNB / 4 / 32; it++) {   // 6 iters
    int n = nbase + it * 32 + lg * 8;
    bf16x8 fa0 = *reinterpret_cast<const bf16x8*>(qb_ + (size_t)lr * NPIX + n);
    bf16x8 fa1 = *reinterpret_cast<const bf16x8*>(qb_ + (size_t)(16 + lr) * NPIX + n);
    bf16x8 fb0 = *reinterpret_cast<const bf16x8*>(kb_ + (size_t)lr * NPIX + n);
    bf16x8 fb1 = *reinterpret_cast<const bf16x8*>(kb_ + (size_t)(16 + lr) * NPIX + n);
    a00 = __builtin_amdgcn_mfma_f32_16x16x32_bf16(fa0, fb0, a00, 0, 0, 0);
    a01 = __builtin_amdgcn_mfma_f32_16x16x32_bf16(fa0, fb1, a01, 0, 0, 0);
    a10 = __builtin_amdgcn_mfma_f32_16x16x32_bf16(fa1, fb0, a10, 0, 0, 0);
    a11 = __builtin_amdgcn_mfma_f32_16x16x32_bf16(fa1, fb1, a11, 0, 0, 0);
    #pragma unroll
    for (int j = 0; j < 8; j++) {
      float q0 = b2f((u16)fa0[j]), q1 = b2f((u16)fa1[j]);
      float k0 = b2f((u16)fb0[j]), k1 = b2f((u16)fb1[j]);
      sq0 += q0 * q0; sq1 += q1 * q1; sk0 += k0 * k0; sk1 += k1 * k1;
    }
  }
  // A-frag row = c (within tile), B col = d, D: row=(lg*4+r within mt tile), col=lr
  #pragma unroll
  for (int r = 0; r < 4; r++) {
    gred[wv][(0  + lg * 4 + r) * 32 + 0  + lr] = a00[r];
    gred[wv][(0  + lg * 4 + r) * 32 + 16 + lr] = a01[r];
    gred[wv][(16 + lg * 4 + r) * 32 + 0  + lr] = a10[r];
    gred[wv][(16 + lg * 4 + r) * 32 + 16 + lr] = a11[r];
  }
  // norms: reduce over 4 lane-groups
  sq0 += __shfl_xor(sq0, 16); sq0 += __shfl_xor(sq0, 32);
  sq1 += __shfl_xor(sq1, 16); sq1 += __shfl_xor(sq1, 32);
  sk0 += __shfl_xor(sk0, 16); sk0 += __shfl_xor(sk0, 32);
  sk1 += __shfl_xor(sk1, 16); sk1 += __shfl_xor(sk1, 32);
  if (lg == 0) {
    atomicAdd(&nq[bh * 32 + lr], sq0);
    atomicAdd(&nq[bh * 32 + 16 + lr], sq1);
    atomicAdd(&nk[bh * 32 + lr], sk0);
    atomicAdd(&nk[bh * 32 + 16 + lr], sk1);
  }
  __syncthreads();
  for (int i = tid; i < 1024; i += 256) {
    float s = gred[0][i] + gred[1][i] + gred[2][i] + gred[3][i];
    atomicAdd(&G[(size_t)bh * 1024 + i], s);
  }
}

// ---------------------------------------------------------------------------
// Kernel 4: normalize + relu + softmax -> A in bf16 FRAGMENT layout.
// ---------------------------------------------------------------------------
__global__ void k_softmax(const float* __restrict__ G, const float* __restrict__ nq,
                          const float* __restrict__ nk, const float* __restrict__ temp,
                          u16* __restrict__ Af, int b0)
{
  int bh = b0 * NHEADS + blockIdx.x;
  int c = threadIdx.x;          // 32 rows
  int hd = bh % NHEADS;
  float tmp = temp[hd];
  float nqc = fmaxf(sqrtf(nq[bh * 32 + c]), 1e-12f);
  float a[32];
  float m = 0.f;
  #pragma unroll
  for (int d = 0; d < 32; d++) {
    float nkd = fmaxf(sqrtf(nk[bh * 32 + d]), 1e-12f);
    float v = G[(size_t)bh * 1024 + c * 32 + d] / (nqc * nkd) * tmp;
    v = fmaxf(v, 0.f);
    a[d] = v; m = fmaxf(m, v);
  }
  float s = 0.f;
  #pragma unroll
  for (int d = 0; d < 32; d++) { a[d] = expf(a[d] - m); s += a[d]; }
  float inv = 1.f / s;
  // frag layout: A[row=c][k=d]: lane = lg*16 + (c&15) of frag mt=c>>4, elem j=d-8*lg
  #pragma unroll
  for (int lg = 0; lg < 4; lg++) {
    uint4 v;
    v.x = pk2(a[8 * lg + 0] * inv, a[8 * lg + 1] * inv);
    v.y = pk2(a[8 * lg + 2] * inv, a[8 * lg + 3] * inv);
    v.z = pk2(a[8 * lg + 4] * inv, a[8 * lg + 5] * inv);
    v.w = pk2(a[8 * lg + 6] * inv, a[8 * lg + 7] * inv);
    *reinterpret_cast<uint4*>(Af + ((size_t)(bh * 2 + (c >> 4)) * 64 + lg * 16 + (c & 15)) * 8) = v;
  }
}

// ---------------------------------------------------------------------------
// Kernel 5: AV (per-head K=32) + proj (96->96) via MFMA; y = x + out*betac.
// ---------------------------------------------------------------------------
__global__ __launch_bounds__(256) void k_av_proj(
    const u16* __restrict__ qkv, const u16* __restrict__ Af,
    const u16* __restrict__ pWf, const float* __restrict__ pb,
    const float* __restrict__ x, const float* __restrict__ betac,
    float* __restrict__ y, int b0)
{
  __shared__ __align__(16) u16 vt[PT][104];
  __shared__ __align__(16) u16 avt[PT][104];
  const int tid = threadIdx.x;
  const int nt = NPIX / PT;
  const int bl = blockIdx.x / nt;
  const int tile = blockIdx.x % nt;
  const int b = b0 + bl;
  const int n0 = tile * PT;
  const u16* vb = qkv + ((size_t)bl * C3 + 2 * C) * NPIX + n0;
  for (int i = tid; i < C * PT; i += 256) {
    int c = i >> 6, p = i & 63;
    vt[p][c] = vb[(size_t)c * NPIX + p];
  }
  __syncthreads();
  const int lane = tid & 63, wv = tid >> 6;
  const int lr = lane & 15, lg = lane >> 4;
  const int pcol = wv * 16 + lr;
  const bf16x8* afp = reinterpret_cast<const bf16x8*>(Af);
  #pragma unroll
  for (int h = 0; h < NHEADS; h++) {
    bf16x8 bv = *reinterpret_cast<const bf16x8*>(&vt[pcol][h * 32 + lg * 8]);
    #pragma unroll
    for (int mt = 0; mt < 2; mt++) {
      f32x4 acc = {0.f, 0.f, 0.f, 0.f};
      acc = __builtin_amdgcn_mfma_f32_16x16x32_bf16(
          afp[((size_t)(b * NHEADS + h) * 2 + mt) * 64 + lane], bv, acc, 0, 0, 0);
      int o = h * 32 + mt * 16 + lg * 4;
      u32* dst = reinterpret_cast<u32*>(&avt[pcol][o]);
      dst[0] = pk2(acc[0], acc[1]);
      dst[1] = pk2(acc[2], acc[3]);
    }
  }
  bf16x8 ba[3];
  #pragma unroll
  for (int kt = 0; kt < 3; kt++)
    ba[kt] = *reinterpret_cast<const bf16x8*>(&avt[pcol][kt * 32 + lg * 8]);
  const bf16x8* pwp = reinterpret_cast<const bf16x8*>(pWf);
  const float* xb = x + (size_t)b * C * NPIX + n0 + pcol;
  float* yb = y + (size_t)b * C * NPIX + n0 + pcol;
  for (int mt = 0; mt < 6; mt++) {
    f32x4 acc = {0.f, 0.f, 0.f, 0.f};
    #pragma unroll
    for (int kt = 0; kt < 3; kt++)
      acc = __builtin_amdgcn_mfma_f32_16x16x32_bf16(pwp[(mt * 3 + kt) * 64 + lane], ba[kt], acc, 0, 0, 0);
    #pragma unroll
    for (int r = 0; r < 4; r++) {
      int o = mt * 16 + lg * 4 + r;
      yb[(size_t)o * NPIX] = xb[(size_t)o * NPIX] + (acc[r] + pb[o]) * betac[o];
    }
  }
}

// ---------------------------------------------------------------------------
// Kernel 6: LN2 + conv1 (96->192) + gate + conv2 (96->96) + residual, MFMA.
// In-place on d_out (block-private tile).
// ---------------------------------------------------------------------------
__global__ __launch_bounds__(256) void k_ffn(
    float* __restrict__ y, const float* __restrict__ ln2w,
    const float* __restrict__ ln2b, const u16* __restrict__ c1f,
    const u16* __restrict__ c2f, const float* __restrict__ c1b,
    const float* __restrict__ c2b, const float* __restrict__ gamma)
{
  __shared__ float xs[C][PT + 1];
  __shared__ __align__(16) u16 yt[PT][104];
  __shared__ __align__(16) u16 gt[PT][104];
  __shared__ float mu_s[PT], rs_s[PT];
  __shared__ float lw[C], lb[C];
  const int tid = threadIdx.x;
  const int nt = NPIX / PT;
  const int b = blockIdx.x / nt;
  const int tile = blockIdx.x % nt;
  const int n0 = tile * PT;
  float* yb = y + (size_t)b * C * NPIX + n0;
  for (int i = tid; i < C * PT; i += 256) {
    int c = i >> 6, p = i & 63;
    xs[c][p] = yb[(size_t)c * NPIX + p];
  }
  if (tid < C) { lw[tid] = ln2w[tid]; lb[tid] = ln2b[tid]; }
  __syncthreads();
  float* red = (float*)yt;
  {
    int g = tid >> 6, p = tid & 63;
    float s = 0.f, ss = 0.f;
    for (int c = g * 24; c < g * 24 + 24; c++) { float v = xs[c][p]; s += v; ss += v * v; }
    red[g * 64 + p] = s; red[(4 + g) * 64 + p] = ss;
  }
  __syncthreads();
  if (tid < PT) {
    float s  = red[tid] + red[64 + tid] + red[128 + tid] + red[192 + tid];
    float ss = red[256 + tid] + red[320 + tid] + red[384 + tid] + red[448 + tid];
    float m = s * (1.f / C);
    float var = ss * (1.f / C) - m * m;
    mu_s[tid] = m; rs_s[tid] = rsqrtf(var + EPSV);
  }
  __syncthreads();
  for (int i = tid; i < C * PT; i += 256) {
    int c = i >> 6, p = i & 63;
    yt[p][c] = f2b((xs[c][p] - mu_s[p]) * rs_s[p] * lw[c] + lb[c]);
  }
  __syncthreads();
  const int lane = tid & 63, wv = tid >> 6;
  const int lr = lane & 15, lg = lane >> 4;
  const int pcol = wv * 16 + lr;
  bf16x8 by[3];
  #pragma unroll
  for (int kt = 0; kt < 3; kt++)
    by[kt] = *reinterpret_cast<const bf16x8*>(&yt[pcol][kt * 32 + lg * 8]);
  const bf16x8* w1 = reinterpret_cast<const bf16x8*>(c1f);
  const bf16x8* w2 = reinterpret_cast<const bf16x8*>(c2f);
  for (int mt = 0; mt < 6; mt++) {
    f32x4 a1 = {0.f, 0.f, 0.f, 0.f}, a2 = {0.f, 0.f, 0.f, 0.f};
    #pragma unroll
    for (int kt = 0; kt < 3; kt++) {
      a1 = __builtin_amdgcn_mfma_f32_16x16x32_bf16(w1[(mt * 3 + kt) * 64 + lane], by[kt], a1, 0, 0, 0);
      a2 = __builtin_amdgcn_mfma_f32_16x16x32_bf16(w1[((mt + 6) * 3 + kt) * 64 + lane], by[kt], a2, 0, 0, 0);
    }
    int o = mt * 16 + lg * 4;
    float g0 = (a1[0] + c1b[o + 0]) * (a2[0] + c1b[o + 96]);
    float g1 = (a1[1] + c1b[o + 1]) * (a2[1] + c1b[o + 97]);
    float g2 = (a1[2] + c1b[o + 2]) * (a2[2] + c1b[o + 98]);
    float g3 = (a1[3] + c1b[o + 3]) * (a2[3] + c1b[o + 99]);
    u32* dst = reinterpret_cast<u32*>(&gt[pcol][o]);
    dst[0] = pk2(g0, g1);
    dst[1] = pk2(g2, g3);
  }
  bf16x8 bg[3];
  #pragma unroll
  for (int kt = 0; kt < 3; kt++)
    bg[kt] = *reinterpret_cast<const bf16x8*>(&gt[pcol][kt * 32 + lg * 8]);
  for (int mt = 0; mt < 6; mt++) {
    f32x4 acc = {0.f, 0.f, 0.f, 0.f};
    #pragma unroll
    for (int kt = 0; kt < 3; kt++)
      acc = __builtin_amdgcn_mfma_f32_16x16x32_bf16(w2[(mt * 3 + kt) * 64 + lane], bg[kt], acc, 0, 0, 0);
    #pragma unroll
    for (int r = 0; r < 4; r++) {
      int o = mt * 16 + lg * 4 + r;
      yb[(size_t)o * NPIX + pcol] = xs[o][pcol] + (acc[r] + c2b[o]) * gamma[o];
    }
  }
}

// ---------------------------------------------------------------------------
extern "C" void kernel_launch(void* const* d_in, const int* in_sizes, int n_in,
                              void* d_out, int out_size, void* d_ws, size_t ws_size,
                              hipStream_t stream)
{
  const float* x     = (const float*)d_in[0];
  const float* ln1w  = (const float*)d_in[1];
  const float* ln1b  = (const float*)d_in[2];
  const float* ln2w  = (const float*)d_in[3];
  const float* ln2b  = (const float*)d_in[4];
  const float* qkvw  = (const float*)d_in[5];
  const float* qkvb  = (const float*)d_in[6];
  const float* dww   = (const float*)d_in[7];
  const float* dwb   = (const float*)d_in[8];
  const float* temp  = (const float*)d_in[9];
  const float* pw    = (const float*)d_in[10];
  const float* pb    = (const float*)d_in[11];
  const float* c1w   = (const float*)d_in[12];
  const float* c1b   = (const float*)d_in[13];
  const float* c2w   = (const float*)d_in[14];
  const float* c2b   = (const float*)d_in[15];
  const float* betac = (const float*)d_in[16];
  const float* gamma = (const float*)d_in[17];
  float* out = (float*)d_out;   // doubles as y storage

  char* ws = (char*)d_ws;
  size_t off = 0;
  float* G  = (float*)(ws + off); off += (size_t)BB * NHEADS * 1024 * sizeof(float);
  float* nq = (float*)(ws + off); off += (size_t)BB * NHEADS * 32 * sizeof(float);
  float* nk = (float*)(ws + off); off += (size_t)BB * NHEADS * 32 * sizeof(float);
  u16* Af   = (u16*)(ws + off);   off += (size_t)BB * NHEADS * 2 * 64 * 8 * sizeof(u16);
  u16* Wf   = (u16*)(ws + off);   off += (size_t)64512 * sizeof(u16);
  off = (off + 255) & ~(size_t)255;

  const size_t per_batch = 2 * (size_t)C3 * NPIX * sizeof(u16);  // ~40.5 MB
  int cb = 8;
  while (cb > 1 && off + (size_t)cb * per_batch > ws_size) cb >>= 1;
  if (off + (size_t)cb * per_batch > ws_size) return;
  u16* qkv_pre = (u16*)(ws + off);
  u16* qkvq    = qkv_pre + (size_t)cb * C3 * NPIX;

  const u16* projWf = Wf + 27648;
  const u16* c1f    = Wf + 36864;
  const u16* c2f    = Wf + 55296;

  hipMemsetAsync(G, 0, (size_t)(BB * NHEADS * 1024 + 2 * BB * NHEADS * 32) * sizeof(float),
                 stream);
  k_prep<<<32, 256, 0, stream>>>(qkvw, pw, c1w, c2w, Wf);

  for (int b0 = 0; b0 < BB; b0 += cb) {
    k_ln1_qkv<<<cb * (NPIX / PT), 256, 0, stream>>>(x, ln1w, ln1b, Wf, qkvb, qkv_pre, b0);
    long quads = (long)cb * C3 * HH * (WW / 4);
    k_dwconv<<<(int)(quads / 256), 256, 0, stream>>>(qkv_pre, dww, dwb, qkvq);
    k_gram<<<cb * NHEADS * (NPIX / GNB), 256, 0, stream>>>(qkvq, G, nq, nk, b0);
    k_softmax<<<cb * NHEADS, 32, 0, stream>>>(G, nq, nk, temp, Af, b0);
    k_av_proj<<<cb * (NPIX / PT), 256, 0, stream>>>(qkvq, Af, projWf, pb, x, betac, out, b0);
  }

  k_ffn<<<BB * (NPIX / PT), 256, 0, stream>>>(out, ln2w, ln2b, c1f, c2f, c1b, c2b, gamma);
}

// Round 5
// 587.999 us; speedup vs baseline: 1.9948x; 1.2213x over previous
//
#include <hip/hip_runtime.h>

#define BB 8
#define C 96
#define HH 192
#define WW 192
#define NPIX (HH*WW)          // 36864
#define C3 (3*C)              // 288
#define NHEADS 3
#define FFND 192
#define EPSV 1e-6f
#define PT 64                 // position tile for GEMM kernels
#define GNB 768               // gram n-block
#define DWR 32                // dwconv rows per block

typedef unsigned short u16;
typedef unsigned int u32;
typedef __attribute__((ext_vector_type(8))) short bf16x8;
typedef __attribute__((ext_vector_type(4))) float f32x4;

__device__ __forceinline__ float b2f(u16 h) {
  u32 u = ((u32)h) << 16;
  return __builtin_bit_cast(float, u);
}
__device__ __forceinline__ u16 f2b(float f) {
  u32 u = __builtin_bit_cast(u32, f);
  u32 r = (u + 0x7FFFu + ((u >> 16) & 1u)) >> 16;
  return (u16)r;
}
__device__ __forceinline__ u32 pk2(float a, float b) {
  return (u32)f2b(a) | ((u32)f2b(b) << 16);
}

// Weight fragment layout: for W[O][96] row-major fp32, fragment f = mt*3+kt,
// lane slot l, elem j holds W[mt*16 + (l&15)][kt*32 + 8*(l>>4) + j] as bf16.
// Used as A: row index = l&15.  Used as B: col index = l&15.  (same packing)
// Offsets in Wf (elements): qkv 0, proj 27648, c1 36864, c2 55296.

// ---------------------------------------------------------------------------
// Prep: convert all 1x1-conv weights to fragment-ready bf16
// ---------------------------------------------------------------------------
__global__ __launch_bounds__(256) void k_prep(
    const float* __restrict__ qkvw, const float* __restrict__ pw,
    const float* __restrict__ c1w, const float* __restrict__ c2w,
    u16* __restrict__ Wf)
{
  int t = blockIdx.x * 256 + threadIdx.x;   // lane-frag id, 8064 total
  const float* src; u16* dst; int tl;
  if (t < 3456)      { src = qkvw; dst = Wf;         tl = t; }
  else if (t < 4608) { src = pw;   dst = Wf + 27648; tl = t - 3456; }
  else if (t < 6912) { src = c1w;  dst = Wf + 36864; tl = t - 4608; }
  else if (t < 8064) { src = c2w;  dst = Wf + 55296; tl = t - 6912; }
  else return;
  int fid = tl >> 6, lane = tl & 63;
  int mt = fid / 3, kt = fid % 3;
  int row = mt * 16 + (lane & 15), k0 = kt * 32 + (lane >> 4) * 8;
  const float* s = src + row * 96 + k0;
  uint4 v;
  v.x = pk2(s[0], s[1]); v.y = pk2(s[2], s[3]);
  v.z = pk2(s[4], s[5]); v.w = pk2(s[6], s[7]);
  *reinterpret_cast<uint4*>(dst + (size_t)tl * 8) = v;
}

// ---------------------------------------------------------------------------
// Kernel 1: LN1 + qkv conv (96->288) via MFMA, out bf16 qkv_pre.
// Epilogue: swapped-operand MFMA -> lane holds 4 consecutive pixels, packed
// uint2 (4x bf16) stores.
// ---------------------------------------------------------------------------
__global__ __launch_bounds__(256) void k_ln1_qkv(
    const float* __restrict__ x, const float* __restrict__ ln1w,
    const float* __restrict__ ln1b, const u16* __restrict__ Wf,
    const float* __restrict__ qb, u16* __restrict__ qkv_pre, int b0)
{
  __shared__ float xs[C][PT + 1];
  __shared__ __align__(16) u16 xt[PT][104];
  __shared__ float mu_s[PT], rs_s[PT];
  __shared__ float lw[C], lb[C];
  const int tid = threadIdx.x;
  const int nt = NPIX / PT;            // 576
  const int bl = blockIdx.x / nt;
  const int tile = blockIdx.x % nt;
  const int n0 = tile * PT;
  const float* xb = x + (size_t)(b0 + bl) * C * NPIX + n0;
  for (int i = tid; i < C * PT; i += 256) {
    int c = i >> 6, p = i & 63;
    xs[c][p] = xb[(size_t)c * NPIX + p];
  }
  if (tid < C) { lw[tid] = ln1w[tid]; lb[tid] = ln1b[tid]; }
  __syncthreads();
  float* red = (float*)xt;   // scratch [8][64] inside xt (written later)
  {
    int g = tid >> 6, p = tid & 63;
    float s = 0.f, ss = 0.f;
    for (int c = g * 24; c < g * 24 + 24; c++) { float v = xs[c][p]; s += v; ss += v * v; }
    red[g * 64 + p] = s; red[(4 + g) * 64 + p] = ss;
  }
  __syncthreads();
  if (tid < PT) {
    float s  = red[tid] + red[64 + tid] + red[128 + tid] + red[192 + tid];
    float ss = red[256 + tid] + red[320 + tid] + red[384 + tid] + red[448 + tid];
    float m = s * (1.f / C);
    float var = ss * (1.f / C) - m * m;
    mu_s[tid] = m; rs_s[tid] = rsqrtf(var + EPSV);
  }
  __syncthreads();
  for (int i = tid; i < C * PT; i += 256) {
    int c = i >> 6, p = i & 63;
    xt[p][c] = f2b((xs[c][p] - mu_s[p]) * rs_s[p] * lw[c] + lb[c]);
  }
  __syncthreads();
  const int lane = tid & 63, wv = tid >> 6;
  const int lr = lane & 15, lg = lane >> 4;
  const int pcol = wv * 16 + lr;
  bf16x8 bf[3];
  #pragma unroll
  for (int kt = 0; kt < 3; kt++)
    bf[kt] = *reinterpret_cast<const bf16x8*>(&xt[pcol][kt * 32 + lg * 8]);
  const bf16x8* wfp = reinterpret_cast<const bf16x8*>(Wf);
  u16* outb = qkv_pre + (size_t)bl * C3 * NPIX + n0 + wv * 16 + lg * 4;
  for (int mt = 0; mt < 18; mt++) {
    f32x4 acc = {0.f, 0.f, 0.f, 0.f};
    #pragma unroll
    for (int kt = 0; kt < 3; kt++)
      acc = __builtin_amdgcn_mfma_f32_16x16x32_bf16(bf[kt], wfp[(mt * 3 + kt) * 64 + lane], acc, 0, 0, 0);
    int o = mt * 16 + lr;
    float bv = qb[o];
    uint2 pk;
    pk.x = pk2(acc[0] + bv, acc[1] + bv);
    pk.y = pk2(acc[2] + bv, acc[3] + bv);
    *reinterpret_cast<uint2*>(outb + (size_t)o * NPIX) = pk;
  }
}

// ---------------------------------------------------------------------------
// Kernel 2: depthwise 3x3 SAME, bf16 -> bf16.  Block = (channel, 32-row band).
// Stage 34 rows x 192 cols in LDS (stride 200 to break bank aliasing);
// each thread computes 8 consecutive outputs via one 16B load/store.
// ---------------------------------------------------------------------------
__global__ __launch_bounds__(256) void k_dwconv(
    const u16* __restrict__ src, const float* __restrict__ dww,
    const float* __restrict__ dwb, u16* __restrict__ dst)
{
  const int ch = blockIdx.x, band = blockIdx.y, bl = blockIdx.z;
  const int tid = threadIdx.x;
  const u16* p = src + ((size_t)bl * C3 + ch) * NPIX;
  u16* q = dst + ((size_t)bl * C3 + ch) * NPIX;
  const int h0 = band * DWR;
  __shared__ __align__(16) u16 rows[(DWR + 2) * 200];
  for (int i = tid; i < (DWR + 2) * 24; i += 256) {
    int r = i / 24, seg = i % 24;
    int h = h0 - 1 + r;
    uint4 v = {0u, 0u, 0u, 0u};
    if (h >= 0 && h < HH)
      v = *reinterpret_cast<const uint4*>(p + (size_t)h * WW + seg * 8);
    *reinterpret_cast<uint4*>(&rows[r * 200 + seg * 8]) = v;
  }
  float wgt[9];
  #pragma unroll
  for (int i = 0; i < 9; i++) wgt[i] = dww[ch * 9 + i];
  const float bias = dwb[ch];
  __syncthreads();
  #pragma unroll
  for (int it = 0; it < 3; it++) {
    int i = it * 256 + tid;
    int r = i / 24, seg = i % 24;
    float o0 = bias, o1 = bias, o2 = bias, o3 = bias;
    float o4 = bias, o5 = bias, o6 = bias, o7 = bias;
    #pragma unroll
    for (int dr = 0; dr < 3; dr++) {
      const u16* rp = &rows[(r + dr) * 200 + seg * 8];
      uint4 cv = *reinterpret_cast<const uint4*>(rp);
      float c0 = b2f((u16)(cv.x & 0xffff)), c1 = b2f((u16)(cv.x >> 16));
      float c2 = b2f((u16)(cv.y & 0xffff)), c3 = b2f((u16)(cv.y >> 16));
      float c4 = b2f((u16)(cv.z & 0xffff)), c5 = b2f((u16)(cv.z >> 16));
      float c6 = b2f((u16)(cv.w & 0xffff)), c7 = b2f((u16)(cv.w >> 16));
      float lf = (seg > 0)  ? b2f(rp[-1]) : 0.f;
      float rg = (seg < 23) ? b2f(rp[8])  : 0.f;
      float wA = wgt[dr * 3 + 0], wB = wgt[dr * 3 + 1], wC = wgt[dr * 3 + 2];
      o0 += lf * wA + c0 * wB + c1 * wC;
      o1 += c0 * wA + c1 * wB + c2 * wC;
      o2 += c1 * wA + c2 * wB + c3 * wC;
      o3 += c2 * wA + c3 * wB + c4 * wC;
      o4 += c3 * wA + c4 * wB + c5 * wC;
      o5 += c4 * wA + c5 * wB + c6 * wC;
      o6 += c5 * wA + c6 * wB + c7 * wC;
      o7 += c6 * wA + c7 * wB + rg * wC;
    }
    uint4 ov;
    ov.x = pk2(o0, o1); ov.y = pk2(o2, o3);
    ov.z = pk2(o4, o5); ov.w = pk2(o6, o7);
    *reinterpret_cast<uint4*>(q + (size_t)(h0 + r) * WW + seg * 8) = ov;
  }
}

// ---------------------------------------------------------------------------
// Kernel 3: Gram G[c][d] = sum_n q_c[n] k_d[n] via MFMA (contract over n),
// plus row sumsq for q,k. Direct global frag loads, LDS wave-reduce, atomics.
// ---------------------------------------------------------------------------
__global__ __launch_bounds__(256) void k_gram(
    const u16* __restrict__ qkv, float* __restrict__ G,
    float* __restrict__ nq, float* __restrict__ nk, int b0)
{
  __shared__ float gred[4][1024];
  const int tid = threadIdx.x, lane = tid & 63, wv = tid >> 6;
  const int nch = NPIX / GNB;    // 48
  const int bhl = blockIdx.x / nch;
  const int chunk = blockIdx.x % nch;
  const int bl = bhl / NHEADS, hd = bhl % NHEADS;
  const int bh = (b0 + bl) * NHEADS + hd;
  const int lr = lane & 15, lg = lane >> 4;
  const u16* qb_ = qkv + ((size_t)bl * C3 + hd * 32) * NPIX;
  const u16* kb_ = qkv + ((size_t)bl * C3 + C + hd * 32) * NPIX;
  const int nbase = chunk * GNB + wv * (GNB / 4);
  f32x4 a00 = {0,0,0,0}, a01 = {0,0,0,0}, a10 = {0,0,0,0}, a11 = {0,0,0,0};
  float sq0 = 0.f, sq1 = 0.f, sk0 = 0.f, sk1 = 0.f;
  #pragma unroll 2
  for (int it = 0; it < GNB / 4 / 32; it++) {   // 6 iters
    int n = nbase + it * 32 + lg * 8;
    bf16x8 fa0 = *reinterpret_cast<const bf16x8*>(qb_ + (size_t)lr * NPIX + n);
    bf16x8 fa1 = *reinterpret_cast<const bf16x8*>(qb_ + (size_t)(16 + lr) * NPIX + n);
    bf16x8 fb0 = *reinterpret_cast<const bf16x8*>(kb_ + (size_t)lr * NPIX + n);
    bf16x8 fb1 = *reinterpret_cast<const bf16x8*>(kb_ + (size_t)(16 + lr) * NPIX + n);
    a00 = __builtin_amdgcn_mfma_f32_16x16x32_bf16(fa0, fb0, a00, 0, 0, 0);
    a01 = __builtin_amdgcn_mfma_f32_16x16x32_bf16(fa0, fb1, a01, 0, 0, 0);
    a10 = __builtin_amdgcn_mfma_f32_16x16x32_bf16(fa1, fb0, a10, 0, 0, 0);
    a11 = __builtin_amdgcn_mfma_f32_16x16x32_bf16(fa1, fb1, a11, 0, 0, 0);
    #pragma unroll
    for (int j = 0; j < 8; j++) {
      float q0 = b2f((u16)fa0[j]), q1 = b2f((u16)fa1[j]);
      float k0 = b2f((u16)fb0[j]), k1 = b2f((u16)fb1[j]);
      sq0 += q0 * q0; sq1 += q1 * q1; sk0 += k0 * k0; sk1 += k1 * k1;
    }
  }
  #pragma unroll
  for (int r = 0; r < 4; r++) {
    gred[wv][(0  + lg * 4 + r) * 32 + 0  + lr] = a00[r];
    gred[wv][(0  + lg * 4 + r) * 32 + 16 + lr] = a01[r];
    gred[wv][(16 + lg * 4 + r) * 32 + 0  + lr] = a10[r];
    gred[wv][(16 + lg * 4 + r) * 32 + 16 + lr] = a11[r];
  }
  sq0 += __shfl_xor(sq0, 16); sq0 += __shfl_xor(sq0, 32);
  sq1 += __shfl_xor(sq1, 16); sq1 += __shfl_xor(sq1, 32);
  sk0 += __shfl_xor(sk0, 16); sk0 += __shfl_xor(sk0, 32);
  sk1 += __shfl_xor(sk1, 16); sk1 += __shfl_xor(sk1, 32);
  if (lg == 0) {
    atomicAdd(&nq[bh * 32 + lr], sq0);
    atomicAdd(&nq[bh * 32 + 16 + lr], sq1);
    atomicAdd(&nk[bh * 32 + lr], sk0);
    atomicAdd(&nk[bh * 32 + 16 + lr], sk1);
  }
  __syncthreads();
  for (int i = tid; i < 1024; i += 256) {
    float s = gred[0][i] + gred[1][i] + gred[2][i] + gred[3][i];
    atomicAdd(&G[(size_t)bh * 1024 + i], s);
  }
}

// ---------------------------------------------------------------------------
// Kernel 4: normalize + relu + softmax -> A in bf16 FRAGMENT layout.
// ---------------------------------------------------------------------------
__global__ void k_softmax(const float* __restrict__ G, const float* __restrict__ nq,
                          const float* __restrict__ nk, const float* __restrict__ temp,
                          u16* __restrict__ Af, int b0)
{
  int bh = b0 * NHEADS + blockIdx.x;
  int c = threadIdx.x;          // 32 rows
  int hd = bh % NHEADS;
  float tmp = temp[hd];
  float nqc = fmaxf(sqrtf(nq[bh * 32 + c]), 1e-12f);
  float a[32];
  float m = 0.f;
  #pragma unroll
  for (int d = 0; d < 32; d++) {
    float nkd = fmaxf(sqrtf(nk[bh * 32 + d]), 1e-12f);
    float v = G[(size_t)bh * 1024 + c * 32 + d] / (nqc * nkd) * tmp;
    v = fmaxf(v, 0.f);
    a[d] = v; m = fmaxf(m, v);
  }
  float s = 0.f;
  #pragma unroll
  for (int d = 0; d < 32; d++) { a[d] = expf(a[d] - m); s += a[d]; }
  float inv = 1.f / s;
  #pragma unroll
  for (int lg = 0; lg < 4; lg++) {
    uint4 v;
    v.x = pk2(a[8 * lg + 0] * inv, a[8 * lg + 1] * inv);
    v.y = pk2(a[8 * lg + 2] * inv, a[8 * lg + 3] * inv);
    v.z = pk2(a[8 * lg + 4] * inv, a[8 * lg + 5] * inv);
    v.w = pk2(a[8 * lg + 6] * inv, a[8 * lg + 7] * inv);
    *reinterpret_cast<uint4*>(Af + ((size_t)(bh * 2 + (c >> 4)) * 64 + lg * 16 + (c & 15)) * 8) = v;
  }
}

// ---------------------------------------------------------------------------
// Kernel 5: AV (per-head K=32) + proj (96->96) via MFMA; y = x + out*betac.
// Proj uses swapped operands -> float4 global read/modify/write.
// ---------------------------------------------------------------------------
__global__ __launch_bounds__(256) void k_av_proj(
    const u16* __restrict__ qkv, const u16* __restrict__ Af,
    const u16* __restrict__ pWf, const float* __restrict__ pb,
    const float* __restrict__ x, const float* __restrict__ betac,
    float* __restrict__ y, int b0)
{
  __shared__ __align__(16) u16 vt[PT][104];
  __shared__ __align__(16) u16 avt[PT][104];
  const int tid = threadIdx.x;
  const int nt = NPIX / PT;
  const int bl = blockIdx.x / nt;
  const int tile = blockIdx.x % nt;
  const int b = b0 + bl;
  const int n0 = tile * PT;
  const u16* vb = qkv + ((size_t)bl * C3 + 2 * C) * NPIX + n0;
  for (int i = tid; i < C * PT; i += 256) {
    int c = i >> 6, p = i & 63;
    vt[p][c] = vb[(size_t)c * NPIX + p];
  }
  __syncthreads();
  const int lane = tid & 63, wv = tid >> 6;
  const int lr = lane & 15, lg = lane >> 4;
  const int pcol = wv * 16 + lr;
  const bf16x8* afp = reinterpret_cast<const bf16x8*>(Af);
  #pragma unroll
  for (int h = 0; h < NHEADS; h++) {
    bf16x8 bv = *reinterpret_cast<const bf16x8*>(&vt[pcol][h * 32 + lg * 8]);
    #pragma unroll
    for (int mt = 0; mt < 2; mt++) {
      f32x4 acc = {0.f, 0.f, 0.f, 0.f};
      acc = __builtin_amdgcn_mfma_f32_16x16x32_bf16(
          afp[((size_t)(b * NHEADS + h) * 2 + mt) * 64 + lane], bv, acc, 0, 0, 0);
      int o = h * 32 + mt * 16 + lg * 4;
      u32* dst = reinterpret_cast<u32*>(&avt[pcol][o]);
      dst[0] = pk2(acc[0], acc[1]);
      dst[1] = pk2(acc[2], acc[3]);
    }
  }
  bf16x8 ba[3];
  #pragma unroll
  for (int kt = 0; kt < 3; kt++)
    ba[kt] = *reinterpret_cast<const bf16x8*>(&avt[pcol][kt * 32 + lg * 8]);
  const bf16x8* pwp = reinterpret_cast<const bf16x8*>(pWf);
  const float* xb = x + (size_t)b * C * NPIX + n0 + wv * 16 + lg * 4;
  float* yb = y + (size_t)b * C * NPIX + n0 + wv * 16 + lg * 4;
  for (int mt = 0; mt < 6; mt++) {
    f32x4 acc = {0.f, 0.f, 0.f, 0.f};
    #pragma unroll
    for (int kt = 0; kt < 3; kt++)
      acc = __builtin_amdgcn_mfma_f32_16x16x32_bf16(ba[kt], pwp[(mt * 3 + kt) * 64 + lane], acc, 0, 0, 0);
    int o = mt * 16 + lr;
    float bv = pb[o], bt = betac[o];
    float4 xv = *reinterpret_cast<const float4*>(xb + (size_t)o * NPIX);
    float4 yv;
    yv.x = xv.x + (acc[0] + bv) * bt;
    yv.y = xv.y + (acc[1] + bv) * bt;
    yv.z = xv.z + (acc[2] + bv) * bt;
    yv.w = xv.w + (acc[3] + bv) * bt;
    *reinterpret_cast<float4*>(yb + (size_t)o * NPIX) = yv;
  }
}

// ---------------------------------------------------------------------------
// Kernel 6: LN2 + conv1 (96->192) + gate + conv2 (96->96) + residual, MFMA.
// In-place on d_out (block-private tile).  Conv2 swapped -> float4 stores.
// ---------------------------------------------------------------------------
__global__ __launch_bounds__(256) void k_ffn(
    float* __restrict__ y, const float* __restrict__ ln2w,
    const float* __restrict__ ln2b, const u16* __restrict__ c1f,
    const u16* __restrict__ c2f, const float* __restrict__ c1b,
    const float* __restrict__ c2b, const float* __restrict__ gamma)
{
  __shared__ float xs[C][PT + 1];
  __shared__ __align__(16) u16 yt[PT][104];
  __shared__ __align__(16) u16 gt[PT][104];
  __shared__ float mu_s[PT], rs_s[PT];
  __shared__ float lw[C], lb[C];
  const int tid = threadIdx.x;
  const int nt = NPIX / PT;
  const int b = blockIdx.x / nt;
  const int tile = blockIdx.x % nt;
  const int n0 = tile * PT;
  float* yb = y + (size_t)b * C * NPIX + n0;
  for (int i = tid; i < C * PT; i += 256) {
    int c = i >> 6, p = i & 63;
    xs[c][p] = yb[(size_t)c * NPIX + p];
  }
  if (tid < C) { lw[tid] = ln2w[tid]; lb[tid] = ln2b[tid]; }
  __syncthreads();
  float* red = (float*)yt;
  {
    int g = tid >> 6, p = tid & 63;
    float s = 0.f, ss = 0.f;
    for (int c = g * 24; c < g * 24 + 24; c++) { float v = xs[c][p]; s += v; ss += v * v; }
    red[g * 64 + p] = s; red[(4 + g) * 64 + p] = ss;
  }
  __syncthreads();
  if (tid < PT) {
    float s  = red[tid] + red[64 + tid] + red[128 + tid] + red[192 + tid];
    float ss = red[256 + tid] + red[320 + tid] + red[384 + tid] + red[448 + tid];
    float m = s * (1.f / C);
    float var = ss * (1.f / C) - m * m;
    mu_s[tid] = m; rs_s[tid] = rsqrtf(var + EPSV);
  }
  __syncthreads();
  for (int i = tid; i < C * PT; i += 256) {
    int c = i >> 6, p = i & 63;
    yt[p][c] = f2b((xs[c][p] - mu_s[p]) * rs_s[p] * lw[c] + lb[c]);
  }
  __syncthreads();
  const int lane = tid & 63, wv = tid >> 6;
  const int lr = lane & 15, lg = lane >> 4;
  const int pcol = wv * 16 + lr;
  bf16x8 by[3];
  #pragma unroll
  for (int kt = 0; kt < 3; kt++)
    by[kt] = *reinterpret_cast<const bf16x8*>(&yt[pcol][kt * 32 + lg * 8]);
  const bf16x8* w1 = reinterpret_cast<const bf16x8*>(c1f);
  const bf16x8* w2 = reinterpret_cast<const bf16x8*>(c2f);
  for (int mt = 0; mt < 6; mt++) {
    f32x4 a1 = {0.f, 0.f, 0.f, 0.f}, a2 = {0.f, 0.f, 0.f, 0.f};
    #pragma unroll
    for (int kt = 0; kt < 3; kt++) {
      a1 = __builtin_amdgcn_mfma_f32_16x16x32_bf16(w1[(mt * 3 + kt) * 64 + lane], by[kt], a1, 0, 0, 0);
      a2 = __builtin_amdgcn_mfma_f32_16x16x32_bf16(w1[((mt + 6) * 3 + kt) * 64 + lane], by[kt], a2, 0, 0, 0);
    }
    int o = mt * 16 + lg * 4;
    float g0 = (a1[0] + c1b[o + 0]) * (a2[0] + c1b[o + 96]);
    float g1 = (a1[1] + c1b[o + 1]) * (a2[1] + c1b[o + 97]);
    float g2 = (a1[2] + c1b[o + 2]) * (a2[2] + c1b[o + 98]);
    float g3 = (a1[3] + c1b[o + 3]) * (a2[3] + c1b[o + 99]);
    u32* dst = reinterpret_cast<u32*>(&gt[pcol][o]);
    dst[0] = pk2(g0, g1);
    dst[1] = pk2(g2, g3);
  }
  bf16x8 bg[3];
  #pragma unroll
  for (int kt = 0; kt < 3; kt++)
    bg[kt] = *reinterpret_cast<const bf16x8*>(&gt[pcol][kt * 32 + lg * 8]);
  const int pix = wv * 16 + lg * 4;
  for (int mt = 0; mt < 6; mt++) {
    f32x4 acc = {0.f, 0.f, 0.f, 0.f};
    #pragma unroll
    for (int kt = 0; kt < 3; kt++)
      acc = __builtin_amdgcn_mfma_f32_16x16x32_bf16(bg[kt], w2[(mt * 3 + kt) * 64 + lane], acc, 0, 0, 0);
    int o = mt * 16 + lr;
    float g = gamma[o], cb2 = c2b[o];
    float4 ov;
    ov.x = xs[o][pix + 0] + (acc[0] + cb2) * g;
    ov.y = xs[o][pix + 1] + (acc[1] + cb2) * g;
    ov.z = xs[o][pix + 2] + (acc[2] + cb2) * g;
    ov.w = xs[o][pix + 3] + (acc[3] + cb2) * g;
    *reinterpret_cast<float4*>(yb + (size_t)o * NPIX + pix) = ov;
  }
}

// ---------------------------------------------------------------------------
extern "C" void kernel_launch(void* const* d_in, const int* in_sizes, int n_in,
                              void* d_out, int out_size, void* d_ws, size_t ws_size,
                              hipStream_t stream)
{
  const float* x     = (const float*)d_in[0];
  const float* ln1w  = (const float*)d_in[1];
  const float* ln1b  = (const float*)d_in[2];
  const float* ln2w  = (const float*)d_in[3];
  const float* ln2b  = (const float*)d_in[4];
  const float* qkvw  = (const float*)d_in[5];
  const float* qkvb  = (const float*)d_in[6];
  const float* dww   = (const float*)d_in[7];
  const float* dwb   = (const float*)d_in[8];
  const float* temp  = (const float*)d_in[9];
  const float* pw    = (const float*)d_in[10];
  const float* pb    = (const float*)d_in[11];
  const float* c1w   = (const float*)d_in[12];
  const float* c1b   = (const float*)d_in[13];
  const float* c2w   = (const float*)d_in[14];
  const float* c2b   = (const float*)d_in[15];
  const float* betac = (const float*)d_in[16];
  const float* gamma = (const float*)d_in[17];
  float* out = (float*)d_out;   // doubles as y storage

  char* ws = (char*)d_ws;
  size_t off = 0;
  float* G  = (float*)(ws + off); off += (size_t)BB * NHEADS * 1024 * sizeof(float);
  float* nq = (float*)(ws + off); off += (size_t)BB * NHEADS * 32 * sizeof(float);
  float* nk = (float*)(ws + off); off += (size_t)BB * NHEADS * 32 * sizeof(float);
  u16* Af   = (u16*)(ws + off);   off += (size_t)BB * NHEADS * 2 * 64 * 8 * sizeof(u16);
  u16* Wf   = (u16*)(ws + off);   off += (size_t)64512 * sizeof(u16);
  off = (off + 255) & ~(size_t)255;

  const size_t per_batch = 2 * (size_t)C3 * NPIX * sizeof(u16);  // ~40.5 MB
  int cb = 8;
  while (cb > 1 && off + (size_t)cb * per_batch > ws_size) cb >>= 1;
  if (off + (size_t)cb * per_batch > ws_size) return;
  u16* qkv_pre = (u16*)(ws + off);
  u16* qkvq    = qkv_pre + (size_t)cb * C3 * NPIX;

  const u16* projWf = Wf + 27648;
  const u16* c1f    = Wf + 36864;
  const u16* c2f    = Wf + 55296;

  hipMemsetAsync(G, 0, (size_t)(BB * NHEADS * 1024 + 2 * BB * NHEADS * 32) * sizeof(float),
                 stream);
  k_prep<<<32, 256, 0, stream>>>(qkvw, pw, c1w, c2w, Wf);

  for (int b0 = 0; b0 < BB; b0 += cb) {
    k_ln1_qkv<<<cb * (NPIX / PT), 256, 0, stream>>>(x, ln1w, ln1b, Wf, qkvb, qkv_pre, b0);
    k_dwconv<<<dim3(C3, HH / DWR, cb), 256, 0, stream>>>(qkv_pre, dww, dwb, qkvq);
    k_gram<<<cb * NHEADS * (NPIX / GNB), 256, 0, stream>>>(qkvq, G, nq, nk, b0);
    k_softmax<<<cb * NHEADS, 32, 0, stream>>>(G, nq, nk, temp, Af, b0);
    k_av_proj<<<cb * (NPIX / PT), 256, 0, stream>>>(qkvq, Af, projWf, pb, x, betac, out, b0);
  }

  k_ffn<<<BB * (NPIX / PT), 256, 0, stream>>>(out, ln2w, ln2b, c1f, c2f, c1b, c2b, gamma);
}